// Round 18
// baseline (1805.828 us; speedup 1.0000x reference)
//
#include <hip/hip_runtime.h>
#include <math.h>

#define TT 256
#define BB 256
#define ID 512
#define HD 512
#define G4 2048            // 4*H
#define KT 1024            // IN + H
#define TBH ((size_t)TT * BB * HD)
#define SPLIT 4            // depths [0,SPLIT) get dedicated launches
#define DGRID 512          // lstm_depth grid (multiple of 4)
#define NDEEP 32           // lstm_deep blocks (1/CU, LDS-resident weights)

typedef short bf16x8 __attribute__((ext_vector_type(8)));
typedef float f32x4  __attribute__((ext_vector_type(4)));
typedef unsigned short u16;
typedef unsigned char  u8;
typedef unsigned int   u32;
typedef u16  u16x8 __attribute__((ext_vector_type(8)));
typedef u16  u16x4 __attribute__((ext_vector_type(4)));

__device__ __forceinline__ u16 f2b(float f) {
    unsigned u = __builtin_bit_cast(unsigned, f);
    return (u16)((u + 0x7fffu + ((u >> 16) & 1u)) >> 16);   // RNE
}
__device__ __forceinline__ float sigm(float x) { return 1.f / (1.f + __expf(-x)); }
__device__ __forceinline__ float tanh_f(float x) { return 1.f - 2.f / (1.f + __expf(2.f * x)); }

// ===========================================================================
// FAST PATH (needs ~133 MB ws)
// ===========================================================================

// Wfrag: fused-K weights, fragment-sequential per (nb, gate, hc) slice
// (validated R11-R17). Also zeroes the deep-kernel barrier.
__global__ void prep_w(const float* __restrict__ W_ih,
                       const float* __restrict__ W_hh,
                       const float* __restrict__ b_ih,
                       const float* __restrict__ b_hh,
                       u16* __restrict__ Wfrag, float* __restrict__ bc,
                       unsigned* __restrict__ bar) {
    int idx = blockIdx.x * 256 + threadIdx.x;   // 0 .. 262143 (16B chunks)
    int s  = idx >> 11;
    int kk = (idx >> 6) & 31;
    int l  = idx & 63;
    int nb = s >> 3, G = (s >> 1) & 3, hc = s & 1;
    int col = G * 512 + nb * 32 + hc * 16 + (l & 15);
    int k0  = kk * 32 + (l >> 4) * 8;
    const float* src = (k0 < ID) ? (W_ih + (size_t)col * ID + k0)
                                 : (W_hh + (size_t)col * HD + (k0 - ID));
    u16x8 pk;
    #pragma unroll
    for (int e = 0; e < 8; ++e) pk[e] = f2b(src[e]);
    *reinterpret_cast<u16x8*>(Wfrag + (size_t)idx * 8) = pk;
    if (idx < G4) bc[idx] = b_ih[idx] + b_hh[idx];
    if (idx < 256) bar[idx] = 0u;
}

// feat (f32) -> xb (bf16, row-major) once.
__global__ void prep_x(const float* __restrict__ feat, u16* __restrict__ xb) {
    size_t base = ((size_t)blockIdx.x * 256 + threadIdx.x) * 8;
    const float4* src = reinterpret_cast<const float4*>(feat + base);
    float4 v0 = src[0], v1 = src[1];
    u16x8 pk;
    pk[0]=f2b(v0.x); pk[1]=f2b(v0.y); pk[2]=f2b(v0.z); pk[3]=f2b(v0.w);
    pk[4]=f2b(v1.x); pk[5]=f2b(v1.y); pk[6]=f2b(v1.z); pk[7]=f2b(v1.w);
    *reinterpret_cast<u16x8*>(xb + base) = pk;
}

// Segment bucketing (deterministic, no atomics; validated R14-R17).
// entries sorted by (d, t, b): entries[slot] = (t<<8)|b. counts[256] = maxd.
__launch_bounds__(256, 1)
__global__ void seg_all(const int* __restrict__ mask,
                        u8*  __restrict__ dmap,
                        u32* __restrict__ counts,
                        u32* __restrict__ offsets,
                        u32* __restrict__ entries) {
    __shared__ u16 c2[256 * 256];   // [d][t] counters -> cursors
    __shared__ u32 aux[256];
    const int tid = threadIdx.x;

    for (int d = 0; d < 256; ++d) c2[d * 256 + tid] = 0;
    __syncthreads();

    {   // phase 1 (tid = b): depths -> dmap
        int d = 0;
        for (int t = 0; t < 256; ++t) {
            int m = mask[t * 256 + tid];
            d = (t == 0) ? 0 : (m ? 0 : d + 1);
            dmap[t * 256 + tid] = (u8)d;
        }
    }
    __syncthreads();

    // phase 2 (tid = t): per-(d,t) counts
    for (int b = 0; b < 256; ++b)
        c2[(int)dmap[tid * 256 + b] * 256 + tid]++;
    __syncthreads();

    {   // phase 3 (tid = d): exclusive prefix over t; total -> aux
        u32 run = 0;
        for (int t = 0; t < 256; ++t) {
            u32 v = c2[tid * 256 + t];
            c2[tid * 256 + t] = (u16)run;
            run += v;
        }
        aux[tid] = run;
    }
    __syncthreads();

    // phase 4: serial prefix over depths + max depth
    if (tid == 0) {
        u32 run = 0; int maxd = 0;
        for (int d = 0; d < 256; ++d) {
            u32 v = aux[d];
            counts[d]  = v;
            offsets[d] = run;
            aux[d] = run;
            run += v;
            if (v) maxd = d;
        }
        counts[256] = (u32)maxd;
    }
    __syncthreads();

    {   // phase 5 (tid = d): add depth offset -> cursors
        u32 o = aux[tid];
        for (int t = 0; t < 256; ++t)
            c2[tid * 256 + t] = (u16)(c2[tid * 256 + t] + o);
    }
    __syncthreads();

    // phase 6 (tid = t): scatter; cursor column owned per-t thread
    for (int b = 0; b < 256; ++b) {
        int d = dmap[tid * 256 + b];
        u32 slot = c2[d * 256 + tid]++;
        entries[slot] = (u32)((tid << 8) | b);
    }
}

// One job = 64 gathered rows x 128 hcols (cg) x 4 gates, K fused.
// Wave hq in [0,8): acc[fr][g]; A reused 4x, B reused 4x (R14 GEMM).
// Epilogue v2: wave-private LDS transpose -> each lane owns 4 consecutive
// hcols of ONE row -> dwordx4 stores (full 64B sectors, no RMW fills).
__device__ __forceinline__ void depth_job(
    int s, int j, int gcnt, int goff,
    const u32* __restrict__ entries,
    const u16* __restrict__ Wfrag,
    const u16* __restrict__ xb,
    u16* __restrict__ hb16,
    const float* __restrict__ bc,
    float* __restrict__ out, int tid, float* __restrict__ tlds)
{
    const int w = tid >> 6, lane = tid & 63;
    const int l15 = lane & 15, l4 = lane >> 4;
    const int cg = j & 3, jt = j >> 2;
    const int hq = w;

    float* hxs0 = out;
    float* hxs1 = out + TBH;
    float* cxs  = out + 2 * TBH;

    const u16* xa[4];
    const u16* ha[4];
    #pragma unroll
    for (int fr = 0; fr < 4; ++fr) {
        int ia = jt * 64 + fr * 16 + l15;
        if (ia >= gcnt) ia = gcnt - 1;
        u32 ea = entries[goff + ia];              // ea == t*256 + b
        xa[fr] = xb   + (size_t)ea * ID + l4 * 8;
        ha[fr] = hb16 + (size_t)(ea - 256) * HD + l4 * 8;  // valid when s>0
    }

    const size_t SL = (size_t)32 * 64 * 8;
    const int hb = cg * 8 + hq;
    const int nb = hb >> 1, hc = hb & 1;
    const u16* wb[4];
    #pragma unroll
    for (int g = 0; g < 4; ++g)
        wb[g] = Wfrag + (size_t)((nb * 4 + g) * 2 + hc) * SL;

    f32x4 acc[4][4] = {};                         // [fr][g]
    #pragma unroll
    for (int kk = 0; kk < 16; ++kk) {             // x part (k 0..511)
        bf16x8 a[4], b[4];
        #pragma unroll
        for (int fr = 0; fr < 4; ++fr)
            a[fr] = *reinterpret_cast<const bf16x8*>(xa[fr] + kk * 32);
        #pragma unroll
        for (int g = 0; g < 4; ++g)
            b[g] = *reinterpret_cast<const bf16x8*>(wb[g] + (size_t)(kk * 64 + lane) * 8);
        #pragma unroll
        for (int fr = 0; fr < 4; ++fr)
            #pragma unroll
            for (int g = 0; g < 4; ++g)
                acc[fr][g] = __builtin_amdgcn_mfma_f32_16x16x32_bf16(a[fr], b[g], acc[fr][g], 0, 0, 0);
    }
    if (s > 0) {                                  // h part (k 512..1023)
        #pragma unroll
        for (int kk = 0; kk < 16; ++kk) {
            bf16x8 a[4], b[4];
            #pragma unroll
            for (int fr = 0; fr < 4; ++fr)
                a[fr] = *reinterpret_cast<const bf16x8*>(ha[fr] + kk * 32);
            #pragma unroll
            for (int g = 0; g < 4; ++g)
                b[g] = *reinterpret_cast<const bf16x8*>(wb[g] + (size_t)((16 + kk) * 64 + lane) * 8);
            #pragma unroll
            for (int fr = 0; fr < 4; ++fr)
                #pragma unroll
                for (int g = 0; g < 4; ++g)
                    acc[fr][g] = __builtin_amdgcn_mfma_f32_16x16x32_bf16(a[fr], b[g], acc[fr][g], 0, 0, 0);
        }
    }

    // ---- epilogue v2: LDS transpose -> vectorized full-sector stores ----
    float* wl = tlds + w * 1280;                  // 4 gates x 16 rows x 20 f32
    const int rowt = lane >> 2;                   // row within 16-tile
    const int colq = lane & 3;                    // 4-col quad
    const int colb = cg * 128 + hq * 16 + colq * 4;
    const f32x4 bI4 = *reinterpret_cast<const f32x4*>(bc + colb);
    const f32x4 bF4 = *reinterpret_cast<const f32x4*>(bc + 512 + colb);
    const f32x4 bG4 = *reinterpret_cast<const f32x4*>(bc + 1024 + colb);
    const f32x4 bO4 = *reinterpret_cast<const f32x4*>(bc + 1536 + colb);

    #pragma unroll
    for (int fr = 0; fr < 4; ++fr) {
        #pragma unroll
        for (int g = 0; g < 4; ++g)
            #pragma unroll
            for (int r = 0; r < 4; ++r)
                wl[g * 320 + (l4 * 4 + r) * 20 + l15] = acc[fr][g][r];
        __syncthreads();

        const int ie = jt * 64 + fr * 16 + rowt;
        const bool act = ie < gcnt;
        const u32 ee = entries[goff + (act ? ie : (gcnt - 1))];
        f32x4 vI = *reinterpret_cast<const f32x4*>(&wl[0 * 320 + rowt * 20 + colq * 4]);
        f32x4 vF = *reinterpret_cast<const f32x4*>(&wl[1 * 320 + rowt * 20 + colq * 4]);
        f32x4 vG = *reinterpret_cast<const f32x4*>(&wl[2 * 320 + rowt * 20 + colq * 4]);
        f32x4 vO = *reinterpret_cast<const f32x4*>(&wl[3 * 320 + rowt * 20 + colq * 4]);

        f32x4 cp = {};
        if (s > 0 && act)
            cp = *reinterpret_cast<const f32x4*>(cxs + ((size_t)(ee - 256) * HD + colb));

        f32x4 hv, cv;
        u16x4 hp;
        #pragma unroll
        for (int q = 0; q < 4; ++q) {
            float ig = sigm(vI[q] + bI4[q]);
            float fg = sigm(vF[q] + bF4[q]);
            float gc = tanh_f(vG[q] + bG4[q]);
            float og = sigm(vO[q] + bO4[q]);
            float c = fg * cp[q] + ig * gc;
            float h = og * tanh_f(c);
            hv[q] = h; cv[q] = c; hp[q] = f2b(h);
        }
        if (act) {
            size_t o = (size_t)ee * HD + colb;
            __builtin_nontemporal_store(hv, reinterpret_cast<f32x4*>(hxs0 + o));
            __builtin_nontemporal_store(hv, reinterpret_cast<f32x4*>(hxs1 + o));
            *reinterpret_cast<f32x4*>(cxs + o) = cv;      // cached full-sector
            *reinterpret_cast<u16x4*>(hb16 + o) = hp;     // cached 8B
        }
        __syncthreads();
    }
}

// Dedicated launches for the big depths [0, SPLIT).
__launch_bounds__(512, 2)
__global__ void lstm_depth(int s,
                           const u32* __restrict__ counts,
                           const u32* __restrict__ offsets,
                           const u32* __restrict__ entries,
                           const u16* __restrict__ Wfrag,
                           const u16* __restrict__ xb,
                           u16* __restrict__ hb16,
                           const float* __restrict__ bc,
                           float* __restrict__ out) {
    __shared__ float tlds[8 * 1280];              // 40 KB transpose staging
    int gcnt = counts[s];
    if (gcnt == 0) return;
    int goff = offsets[s];
    int njobs = ((gcnt + 63) >> 6) << 2;
    for (int j = blockIdx.x; j < njobs; j += DGRID)   // cg = j&3 const per block
        depth_job(s, j, gcnt, goff, entries, Wfrag, xb, hb16, bc, out,
                  threadIdx.x, tlds);
}

// Persistent deep kernel: all depths s in [SPLIT, maxd] in ONE launch.
// 32 blocks; weights staged in LDS ONCE (128 KB; survives barrier acq-inv).
// Validated R17. (Old scattered epilogue kept: data volume here is tiny.)
__launch_bounds__(512, 1)
__global__ void lstm_deep(const u32* __restrict__ counts,
                          const u32* __restrict__ offsets,
                          const u32* __restrict__ entries,
                          const u16* __restrict__ Wfrag,
                          const u16* __restrict__ xb,
                          u16* __restrict__ hb16,
                          const float* __restrict__ bc,
                          float* __restrict__ out,
                          unsigned* bar) {
    __shared__ u16 Wl[4 * 32 * 64 * 8];   // 128 KB: [g][kk][lane][8]
    const int tid = threadIdx.x;
    const int hb = blockIdx.x;            // hcol-16 block
    const int w = tid >> 6, lane = tid & 63;
    const int l15 = lane & 15, l4 = lane >> 4;

    const int maxd = (int)counts[256];
    if (maxd < SPLIT) return;

    {   // stage this block's weight slices
        const int nb = hb >> 1, hc = hb & 1;
        for (int c = tid; c < 4 * 32 * 64; c += 512) {
            int g = c >> 11;
            int rem = c & 2047;
            u16x8 v = *reinterpret_cast<const u16x8*>(
                Wfrag + ((size_t)((nb * 4 + g) * 2 + hc) * 2048 + rem) * 8);
            *reinterpret_cast<u16x8*>(&Wl[(size_t)c * 8]) = v;
        }
    }
    __syncthreads();

    float* hxs0 = out;
    float* hxs1 = out + TBH;
    float* cxs  = out + 2 * TBH;
    const int hcol = hb * 16 + l15;
    const float bI = bc[hcol],        bF = bc[512 + hcol];
    const float bG = bc[1024 + hcol], bO = bc[1536 + hcol];

    unsigned iter = 0;
    for (int s = SPLIT; s <= maxd; ++s) {
        const int gcnt = counts[s];
        const int goff = offsets[s];
        const int ngrp = (gcnt + 63) >> 6;

        for (int grp = w; grp < ngrp; grp += 8) {
            const u16* xa[4];
            const u16* ha[4];
            #pragma unroll
            for (int fr = 0; fr < 4; ++fr) {
                int ia = grp * 64 + fr * 16 + l15;
                if (ia >= gcnt) ia = gcnt - 1;
                u32 ea = entries[goff + ia];
                xa[fr] = xb   + (size_t)ea * ID + l4 * 8;
                ha[fr] = hb16 + (size_t)(ea - 256) * HD + l4 * 8;
            }
            f32x4 acc[4][4] = {};
            #pragma unroll
            for (int kk = 0; kk < 16; ++kk) {             // x part
                bf16x8 a[4], b[4];
                #pragma unroll
                for (int fr = 0; fr < 4; ++fr)
                    a[fr] = *reinterpret_cast<const bf16x8*>(xa[fr] + kk * 32);
                #pragma unroll
                for (int g = 0; g < 4; ++g)
                    b[g] = *reinterpret_cast<const bf16x8*>(&Wl[((g * 32 + kk) * 64 + lane) * 8]);
                #pragma unroll
                for (int fr = 0; fr < 4; ++fr)
                    #pragma unroll
                    for (int g = 0; g < 4; ++g)
                        acc[fr][g] = __builtin_amdgcn_mfma_f32_16x16x32_bf16(a[fr], b[g], acc[fr][g], 0, 0, 0);
            }
            #pragma unroll
            for (int kk = 0; kk < 16; ++kk) {             // h part (s >= SPLIT > 0)
                bf16x8 a[4], b[4];
                #pragma unroll
                for (int fr = 0; fr < 4; ++fr)
                    a[fr] = *reinterpret_cast<const bf16x8*>(ha[fr] + kk * 32);
                #pragma unroll
                for (int g = 0; g < 4; ++g)
                    b[g] = *reinterpret_cast<const bf16x8*>(&Wl[((g * 32 + 16 + kk) * 64 + lane) * 8]);
                #pragma unroll
                for (int fr = 0; fr < 4; ++fr)
                    #pragma unroll
                    for (int g = 0; g < 4; ++g)
                        acc[fr][g] = __builtin_amdgcn_mfma_f32_16x16x32_bf16(a[fr], b[g], acc[fr][g], 0, 0, 0);
            }

            #pragma unroll
            for (int fr = 0; fr < 4; ++fr) {
                #pragma unroll
                for (int r = 0; r < 4; ++r) {
                    int ie = grp * 64 + fr * 16 + l4 * 4 + r;
                    if (ie < gcnt) {
                        u32 ee = entries[goff + ie];
                        float cprev = cxs[(size_t)(ee - 256) * HD + hcol];
                        float ig = sigm(acc[fr][0][r] + bI);
                        float fg = sigm(acc[fr][1][r] + bF);
                        float gc = tanh_f(acc[fr][2][r] + bG);
                        float og = sigm(acc[fr][3][r] + bO);
                        float c = fg * cprev + ig * gc;
                        float h = og * tanh_f(c);
                        size_t o = (size_t)ee * HD + hcol;
                        __builtin_nontemporal_store(h, hxs0 + o);
                        __builtin_nontemporal_store(h, hxs1 + o);
                        cxs[o] = c;
                        unsigned mine = (unsigned)f2b(h);
                        unsigned oth  = (unsigned)__shfl_xor((int)mine, 1, 64);
                        if (!(lane & 1))
                            *reinterpret_cast<unsigned*>(hb16 + o) =
                                (mine & 0xffffu) | (oth << 16);
                    }
                }
            }
        }

        if (s == maxd) break;
        // ---- inter-depth barrier (R4 protocol); weights stay in LDS ----
        asm volatile("s_waitcnt vmcnt(0)" ::: "memory");
        __syncthreads();
        ++iter;
        if (tid == 0) {
            __hip_atomic_fetch_add(bar, 1u, __ATOMIC_RELEASE, __HIP_MEMORY_SCOPE_AGENT);
            while (__hip_atomic_load(bar, __ATOMIC_RELAXED, __HIP_MEMORY_SCOPE_AGENT) < iter * (unsigned)NDEEP)
                __builtin_amdgcn_s_sleep(1);
            (void)__hip_atomic_load(bar, __ATOMIC_ACQUIRE, __HIP_MEMORY_SCOPE_AGENT);
        }
        __syncthreads();
    }
}

// ===========================================================================
// FALLBACK PATH (round-1, validated): per-step launches, fp32 VALU
// ===========================================================================
__global__ void prep_r1(const float* __restrict__ W_ih, const float* __restrict__ W_hh,
                        const float* __restrict__ b_ih, const float* __restrict__ b_hh,
                        float* __restrict__ WcT, float* __restrict__ bc) {
    int idx = blockIdx.x * 256 + threadIdx.x;
    int k = idx >> 11;
    int j = idx & (G4 - 1);
    float v = (k < ID) ? W_ih[(size_t)j * ID + k] : W_hh[(size_t)j * HD + (k - ID)];
    WcT[idx] = v;
    if (idx < G4) bc[idx] = b_ih[idx] + b_hh[idx];
}

__launch_bounds__(512, 2)
__global__ void lstm_step_r1(int t, int use_ws,
                             const float* __restrict__ feat, const int* __restrict__ mask,
                             const float* __restrict__ W_ih, const float* __restrict__ W_hh,
                             const float* __restrict__ b_ih, const float* __restrict__ b_hh,
                             const float* __restrict__ WcT, const float* __restrict__ bc,
                             float* __restrict__ out) {
    __shared__ float4 xh4[16][256];
    const int tid = threadIdx.x;
    const int c0 = blockIdx.x * 32;
    const int b0 = blockIdx.y * 16;
    float* hxs0 = out;
    float* hxs1 = out + TBH;
    float* cxs  = out + 2 * TBH;

    for (int e = tid; e < 16 * 256; e += 512) {
        int bl = e >> 8, q = e & 255, b = b0 + bl;
        float4 v;
        if (q < 128) {
            v = reinterpret_cast<const float4*>(feat + ((size_t)t * BB + b) * ID)[q];
        } else if (t == 0) {
            v = make_float4(0.f, 0.f, 0.f, 0.f);
        } else {
            float keep = 1.0f - (float)mask[t * BB + b];
            v = reinterpret_cast<const float4*>(hxs0 + ((size_t)(t - 1) * BB + b) * HD)[q - 128];
            v.x *= keep; v.y *= keep; v.z *= keep; v.w *= keep;
        }
        xh4[bl][q] = v;
    }
    __syncthreads();

    const int lc = tid & 127, bh = tid >> 7;
    const int j = (lc >> 5) * HD + c0 + (lc & 31);
    float acc[4] = {0.f, 0.f, 0.f, 0.f};
    if (use_ws) {
        for (int k = 0; k < KT; k += 4) {
            float w0 = WcT[(size_t)(k + 0) * G4 + j];
            float w1 = WcT[(size_t)(k + 1) * G4 + j];
            float w2 = WcT[(size_t)(k + 2) * G4 + j];
            float w3 = WcT[(size_t)(k + 3) * G4 + j];
            #pragma unroll
            for (int i = 0; i < 4; ++i) {
                float4 x = xh4[bh * 4 + i][k >> 2];
                acc[i] = fmaf(x.x, w0, acc[i]); acc[i] = fmaf(x.y, w1, acc[i]);
                acc[i] = fmaf(x.z, w2, acc[i]); acc[i] = fmaf(x.w, w3, acc[i]);
            }
        }
    } else {
        const float4* wi = reinterpret_cast<const float4*>(W_ih + (size_t)j * ID);
        const float4* wh = reinterpret_cast<const float4*>(W_hh + (size_t)j * HD);
        for (int k = 0; k < KT; k += 4) {
            float4 wv = (k < ID) ? wi[k >> 2] : wh[(k - ID) >> 2];
            #pragma unroll
            for (int i = 0; i < 4; ++i) {
                float4 x = xh4[bh * 4 + i][k >> 2];
                acc[i] = fmaf(x.x, wv.x, acc[i]); acc[i] = fmaf(x.y, wv.y, acc[i]);
                acc[i] = fmaf(x.z, wv.z, acc[i]); acc[i] = fmaf(x.w, wv.w, acc[i]);
            }
        }
    }
    float gbias = use_ws ? bc[j] : (b_ih[j] + b_hh[j]);
    __syncthreads();
    float* gbuf = reinterpret_cast<float*>(xh4);
    #pragma unroll
    for (int i = 0; i < 4; ++i) gbuf[lc * 16 + bh * 4 + i] = acc[i] + gbias;
    __syncthreads();
    {
        int hc = tid & 31, bl = tid >> 5, b = b0 + bl;
        float keep = 1.0f - (float)mask[t * BB + b];
        float cp = 0.f;
        if (t > 0) cp = cxs[((size_t)(t - 1) * BB + b) * HD + c0 + hc];
        cp *= keep;
        float ig = gbuf[(0 * 32 + hc) * 16 + bl];
        float fg = gbuf[(1 * 32 + hc) * 16 + bl];
        float gg = gbuf[(2 * 32 + hc) * 16 + bl];
        float og = gbuf[(3 * 32 + hc) * 16 + bl];
        ig = 1.0f / (1.0f + __expf(-ig));
        fg = 1.0f / (1.0f + __expf(-fg));
        gg = tanhf(gg);
        og = 1.0f / (1.0f + __expf(-og));
        float cn = fg * cp + ig * gg;
        float hn = og * tanhf(cn);
        size_t o = ((size_t)t * BB + b) * HD + c0 + hc;
        hxs0[o] = hn; hxs1[o] = hn; cxs[o] = cn;
    }
}

// ===========================================================================
extern "C" void kernel_launch(void* const* d_in, const int* in_sizes, int n_in,
                              void* d_out, int out_size, void* d_ws, size_t ws_size,
                              hipStream_t stream) {
    const float* feat = (const float*)d_in[0];
    const int*   mask = (const int*)d_in[1];
    const float* W_ih = (const float*)d_in[2];
    const float* W_hh = (const float*)d_in[3];
    const float* b_ih = (const float*)d_in[4];
    const float* b_hh = (const float*)d_in[5];
    float* out = (float*)d_out;

    size_t offWf  = 0;                                               // 4 MB
    size_t offBc  = offWf  + (size_t)G4 * KT * sizeof(u16);
    size_t offXb  = offBc  + (size_t)G4 * sizeof(float);             // +8 KB
    size_t offHb  = offXb  + (size_t)TT * BB * ID * sizeof(u16);     // +64 MB
    size_t offDm  = offHb  + (size_t)TT * BB * HD * sizeof(u16);     // +64 MB
    size_t offCnt = offDm  + (size_t)TT * BB;                        // +64 KB
    size_t offOff = offCnt + 2048;                                   // counts[257]
    size_t offBar = offOff + 2048;
    size_t offEnt = offBar + 1024;
    size_t need   = offEnt + ((size_t)TT * BB + 256) * sizeof(u32);

    if (d_ws != nullptr && ws_size >= need) {
        char* ws = (char*)d_ws;
        u16*   Wfrag = (u16*)(ws + offWf);
        float* bc    = (float*)(ws + offBc);
        u16*   xb    = (u16*)(ws + offXb);
        u16*   hb16  = (u16*)(ws + offHb);
        u8*    dmap  = (u8*)(ws + offDm);
        u32*   counts  = (u32*)(ws + offCnt);
        u32*   offsets = (u32*)(ws + offOff);
        unsigned* bar  = (unsigned*)(ws + offBar);
        u32*   entries = (u32*)(ws + offEnt);

        prep_w<<<1024, 256, 0, stream>>>(W_ih, W_hh, b_ih, b_hh, Wfrag, bc, bar);
        prep_x<<<16384, 256, 0, stream>>>(feat, xb);
        seg_all<<<1, 256, 0, stream>>>(mask, dmap, counts, offsets, entries);
        for (int s = 0; s < SPLIT; ++s)
            lstm_depth<<<DGRID, 512, 0, stream>>>(s, counts, offsets, entries,
                                                  Wfrag, xb, hb16, bc, out);
        lstm_deep<<<NDEEP, 512, 0, stream>>>(counts, offsets, entries,
                                             Wfrag, xb, hb16, bc, out, bar);
    } else {
        float* WcT = (float*)d_ws;
        float* bcf = WcT + (size_t)KT * G4;
        const size_t ws_needed = ((size_t)KT * G4 + G4) * sizeof(float);
        int use_ws = (d_ws != nullptr && ws_size >= ws_needed) ? 1 : 0;
        if (use_ws)
            prep_r1<<<(KT * G4) / 256, 256, 0, stream>>>(W_ih, W_hh, b_ih, b_hh, WcT, bcf);
        dim3 grid(16, 16);
        for (int t = 0; t < TT; ++t)
            lstm_step_r1<<<grid, 512, 0, stream>>>(t, use_ws, feat, mask,
                                                   W_ih, W_hh, b_ih, b_hh, WcT, bcf, out);
    }
}

// Round 19
// 1722.164 us; speedup vs baseline: 1.0486x; 1.0486x over previous
//
#include <hip/hip_runtime.h>
#include <math.h>

#define TT 256
#define BB 256
#define ID 512
#define HD 512
#define G4 2048            // 4*H
#define KT 1024            // IN + H
#define TBH ((size_t)TT * BB * HD)
#define SPLIT 4            // depths [0,SPLIT) get dedicated launches
#define DGRID 512          // lstm_depth grid (multiple of 4)
#define NDEEP 32           // lstm_deep blocks (1/CU, LDS-resident weights)

typedef short bf16x8 __attribute__((ext_vector_type(8)));
typedef float f32x4  __attribute__((ext_vector_type(4)));
typedef unsigned short u16;
typedef unsigned char  u8;
typedef unsigned int   u32;
typedef u16  u16x8 __attribute__((ext_vector_type(8)));

__device__ __forceinline__ u16 f2b(float f) {
    unsigned u = __builtin_bit_cast(unsigned, f);
    return (u16)((u + 0x7fffu + ((u >> 16) & 1u)) >> 16);   // RNE
}
__device__ __forceinline__ float sigm(float x) { return 1.f / (1.f + __expf(-x)); }
__device__ __forceinline__ float tanh_f(float x) { return 1.f - 2.f / (1.f + __expf(2.f * x)); }

// ===========================================================================
// FAST PATH (needs ~133 MB ws)
// ===========================================================================

// Wfrag: fused-K weights, fragment-sequential per (nb, gate, hc) slice
// (validated R11-R17). Also zeroes the deep-kernel barrier.
__global__ void prep_w(const float* __restrict__ W_ih,
                       const float* __restrict__ W_hh,
                       const float* __restrict__ b_ih,
                       const float* __restrict__ b_hh,
                       u16* __restrict__ Wfrag, float* __restrict__ bc,
                       unsigned* __restrict__ bar) {
    int idx = blockIdx.x * 256 + threadIdx.x;   // 0 .. 262143 (16B chunks)
    int s  = idx >> 11;
    int kk = (idx >> 6) & 31;
    int l  = idx & 63;
    int nb = s >> 3, G = (s >> 1) & 3, hc = s & 1;
    int col = G * 512 + nb * 32 + hc * 16 + (l & 15);
    int k0  = kk * 32 + (l >> 4) * 8;
    const float* src = (k0 < ID) ? (W_ih + (size_t)col * ID + k0)
                                 : (W_hh + (size_t)col * HD + (k0 - ID));
    u16x8 pk;
    #pragma unroll
    for (int e = 0; e < 8; ++e) pk[e] = f2b(src[e]);
    *reinterpret_cast<u16x8*>(Wfrag + (size_t)idx * 8) = pk;
    if (idx < G4) bc[idx] = b_ih[idx] + b_hh[idx];
    if (idx < 256) bar[idx] = 0u;
}

// feat (f32) -> xb (bf16, row-major) once.
__global__ void prep_x(const float* __restrict__ feat, u16* __restrict__ xb) {
    size_t base = ((size_t)blockIdx.x * 256 + threadIdx.x) * 8;
    const float4* src = reinterpret_cast<const float4*>(feat + base);
    float4 v0 = src[0], v1 = src[1];
    u16x8 pk;
    pk[0]=f2b(v0.x); pk[1]=f2b(v0.y); pk[2]=f2b(v0.z); pk[3]=f2b(v0.w);
    pk[4]=f2b(v1.x); pk[5]=f2b(v1.y); pk[6]=f2b(v1.z); pk[7]=f2b(v1.w);
    *reinterpret_cast<u16x8*>(xb + base) = pk;
}

// Segment bucketing (deterministic, no atomics; validated R14-R17).
// entries sorted by (d, t, b): entries[slot] = (t<<8)|b. counts[256] = maxd.
__launch_bounds__(256, 1)
__global__ void seg_all(const int* __restrict__ mask,
                        u8*  __restrict__ dmap,
                        u32* __restrict__ counts,
                        u32* __restrict__ offsets,
                        u32* __restrict__ entries) {
    __shared__ u16 c2[256 * 256];   // [d][t] counters -> cursors
    __shared__ u32 aux[256];
    const int tid = threadIdx.x;

    for (int d = 0; d < 256; ++d) c2[d * 256 + tid] = 0;
    __syncthreads();

    {   // phase 1 (tid = b): depths -> dmap
        int d = 0;
        for (int t = 0; t < 256; ++t) {
            int m = mask[t * 256 + tid];
            d = (t == 0) ? 0 : (m ? 0 : d + 1);
            dmap[t * 256 + tid] = (u8)d;
        }
    }
    __syncthreads();

    // phase 2 (tid = t): per-(d,t) counts
    for (int b = 0; b < 256; ++b)
        c2[(int)dmap[tid * 256 + b] * 256 + tid]++;
    __syncthreads();

    {   // phase 3 (tid = d): exclusive prefix over t; total -> aux
        u32 run = 0;
        for (int t = 0; t < 256; ++t) {
            u32 v = c2[tid * 256 + t];
            c2[tid * 256 + t] = (u16)run;
            run += v;
        }
        aux[tid] = run;
    }
    __syncthreads();

    // phase 4: serial prefix over depths + max depth
    if (tid == 0) {
        u32 run = 0; int maxd = 0;
        for (int d = 0; d < 256; ++d) {
            u32 v = aux[d];
            counts[d]  = v;
            offsets[d] = run;
            aux[d] = run;
            run += v;
            if (v) maxd = d;
        }
        counts[256] = (u32)maxd;
    }
    __syncthreads();

    {   // phase 5 (tid = d): add depth offset -> cursors
        u32 o = aux[tid];
        for (int t = 0; t < 256; ++t)
            c2[tid * 256 + t] = (u16)(c2[tid * 256 + t] + o);
    }
    __syncthreads();

    // phase 6 (tid = t): scatter; cursor column owned per-t thread
    for (int b = 0; b < 256; ++b) {
        int d = dmap[tid * 256 + b];
        u32 slot = c2[d * 256 + tid]++;
        entries[slot] = (u32)((tid << 8) | b);
    }
}

// One job = 64 gathered rows x 128 hcols (cg) x 4 gates, K fused.
// Wave hq in [0,8): acc[fr][g]; A reused 4x, B reused 4x. No LDS/barriers.
// Store policy = R14/R17: NT for hxs0/hxs1, cached for cxs/hb16.
__device__ __forceinline__ void depth_job(
    int s, int j, int gcnt, int goff,
    const u32* __restrict__ entries,
    const u16* __restrict__ Wfrag,
    const u16* __restrict__ xb,
    u16* __restrict__ hb16,
    const float* __restrict__ bc,
    float* __restrict__ out, int tid)
{
    const int w = tid >> 6, lane = tid & 63;
    const int l15 = lane & 15, l4 = lane >> 4;
    const int cg = j & 3, jt = j >> 2;
    const int hq = w;

    float* hxs0 = out;
    float* hxs1 = out + TBH;
    float* cxs  = out + 2 * TBH;

    const u16* xa[4];
    const u16* ha[4];
    #pragma unroll
    for (int fr = 0; fr < 4; ++fr) {
        int ia = jt * 64 + fr * 16 + l15;
        if (ia >= gcnt) ia = gcnt - 1;
        u32 ea = entries[goff + ia];              // ea == t*256 + b
        xa[fr] = xb   + (size_t)ea * ID + l4 * 8;
        ha[fr] = hb16 + (size_t)(ea - 256) * HD + l4 * 8;  // valid when s>0
    }

    const size_t SL = (size_t)32 * 64 * 8;
    const int hb = cg * 8 + hq;
    const int nb = hb >> 1, hc = hb & 1;
    const u16* wb[4];
    #pragma unroll
    for (int g = 0; g < 4; ++g)
        wb[g] = Wfrag + (size_t)((nb * 4 + g) * 2 + hc) * SL;

    f32x4 acc[4][4] = {};                         // [fr][g]
    #pragma unroll
    for (int kk = 0; kk < 16; ++kk) {             // x part (k 0..511)
        bf16x8 a[4], b[4];
        #pragma unroll
        for (int fr = 0; fr < 4; ++fr)
            a[fr] = *reinterpret_cast<const bf16x8*>(xa[fr] + kk * 32);
        #pragma unroll
        for (int g = 0; g < 4; ++g)
            b[g] = *reinterpret_cast<const bf16x8*>(wb[g] + (size_t)(kk * 64 + lane) * 8);
        #pragma unroll
        for (int fr = 0; fr < 4; ++fr)
            #pragma unroll
            for (int g = 0; g < 4; ++g)
                acc[fr][g] = __builtin_amdgcn_mfma_f32_16x16x32_bf16(a[fr], b[g], acc[fr][g], 0, 0, 0);
    }
    if (s > 0) {                                  // h part (k 512..1023)
        #pragma unroll
        for (int kk = 0; kk < 16; ++kk) {
            bf16x8 a[4], b[4];
            #pragma unroll
            for (int fr = 0; fr < 4; ++fr)
                a[fr] = *reinterpret_cast<const bf16x8*>(ha[fr] + kk * 32);
            #pragma unroll
            for (int g = 0; g < 4; ++g)
                b[g] = *reinterpret_cast<const bf16x8*>(wb[g] + (size_t)((16 + kk) * 64 + lane) * 8);
            #pragma unroll
            for (int fr = 0; fr < 4; ++fr)
                #pragma unroll
                for (int g = 0; g < 4; ++g)
                    acc[fr][g] = __builtin_amdgcn_mfma_f32_16x16x32_bf16(a[fr], b[g], acc[fr][g], 0, 0, 0);
        }
    }

    const int hcol = cg * 128 + hq * 16 + l15;
    const float bI = bc[hcol],        bF = bc[512 + hcol];
    const float bG = bc[1024 + hcol], bO = bc[1536 + hcol];
    #pragma unroll
    for (int fr = 0; fr < 4; ++fr) {
        #pragma unroll
        for (int r = 0; r < 4; ++r) {
            int ie = jt * 64 + fr * 16 + l4 * 4 + r;   // uniform across l15
            if (ie < gcnt) {
                u32 ee = entries[goff + ie];
                float cprev = (s > 0) ? cxs[(size_t)(ee - 256) * HD + hcol] : 0.f;
                float ig = sigm(acc[fr][0][r] + bI);
                float fg = sigm(acc[fr][1][r] + bF);
                float gc = tanh_f(acc[fr][2][r] + bG);
                float og = sigm(acc[fr][3][r] + bO);
                float c = fg * cprev + ig * gc;
                float h = og * tanh_f(c);
                size_t o = (size_t)ee * HD + hcol;
                __builtin_nontemporal_store(h, hxs0 + o);
                __builtin_nontemporal_store(h, hxs1 + o);
                cxs[o] = c;                       // cached: read by next depth
                unsigned mine = (unsigned)f2b(h);
                unsigned oth  = (unsigned)__shfl_xor((int)mine, 1, 64);
                if (!(lane & 1))
                    *reinterpret_cast<unsigned*>(hb16 + o) =
                        (mine & 0xffffu) | (oth << 16);
            }
        }
    }
}

// Dedicated launches for the big depths [0, SPLIT).
__launch_bounds__(512, 2)
__global__ void lstm_depth(int s,
                           const u32* __restrict__ counts,
                           const u32* __restrict__ offsets,
                           const u32* __restrict__ entries,
                           const u16* __restrict__ Wfrag,
                           const u16* __restrict__ xb,
                           u16* __restrict__ hb16,
                           const float* __restrict__ bc,
                           float* __restrict__ out) {
    int gcnt = counts[s];
    if (gcnt == 0) return;
    int goff = offsets[s];
    int njobs = ((gcnt + 63) >> 6) << 2;
    for (int j = blockIdx.x; j < njobs; j += DGRID)   // cg = j&3 const per block
        depth_job(s, j, gcnt, goff, entries, Wfrag, xb, hb16, bc, out, threadIdx.x);
}

// Persistent deep kernel: all depths s in [SPLIT, maxd] in ONE launch.
// 32 blocks; block owns hcols [bid*16,+16) x 4 gates, weights staged in LDS
// ONCE (128 KB; survives the barrier's acquire-inv). Wave w takes 64-row
// groups; acc[fr][g] dual-reuse. R4-proven barrier between depths.
__launch_bounds__(512, 1)
__global__ void lstm_deep(const u32* __restrict__ counts,
                          const u32* __restrict__ offsets,
                          const u32* __restrict__ entries,
                          const u16* __restrict__ Wfrag,
                          const u16* __restrict__ xb,
                          u16* __restrict__ hb16,
                          const float* __restrict__ bc,
                          float* __restrict__ out,
                          unsigned* bar) {
    __shared__ u16 Wl[4 * 32 * 64 * 8];   // 128 KB: [g][kk][lane][8]
    const int tid = threadIdx.x;
    const int hb = blockIdx.x;            // hcol-16 block
    const int w = tid >> 6, lane = tid & 63;
    const int l15 = lane & 15, l4 = lane >> 4;

    const int maxd = (int)counts[256];
    if (maxd < SPLIT) return;

    {   // stage this block's weight slices (4 gates x 32 kk x 64 lanes x 16B)
        const int nb = hb >> 1, hc = hb & 1;
        for (int c = tid; c < 4 * 32 * 64; c += 512) {
            int g = c >> 11;
            int rem = c & 2047;
            u16x8 v = *reinterpret_cast<const u16x8*>(
                Wfrag + ((size_t)((nb * 4 + g) * 2 + hc) * 2048 + rem) * 8);
            *reinterpret_cast<u16x8*>(&Wl[(size_t)c * 8]) = v;
        }
    }
    __syncthreads();

    float* hxs0 = out;
    float* hxs1 = out + TBH;
    float* cxs  = out + 2 * TBH;
    const int hcol = hb * 16 + l15;
    const float bI = bc[hcol],        bF = bc[512 + hcol];
    const float bG = bc[1024 + hcol], bO = bc[1536 + hcol];

    unsigned iter = 0;
    for (int s = SPLIT; s <= maxd; ++s) {
        const int gcnt = counts[s];
        const int goff = offsets[s];
        const int ngrp = (gcnt + 63) >> 6;

        for (int grp = w; grp < ngrp; grp += 8) {
            const u16* xa[4];
            const u16* ha[4];
            #pragma unroll
            for (int fr = 0; fr < 4; ++fr) {
                int ia = grp * 64 + fr * 16 + l15;
                if (ia >= gcnt) ia = gcnt - 1;
                u32 ea = entries[goff + ia];
                xa[fr] = xb   + (size_t)ea * ID + l4 * 8;
                ha[fr] = hb16 + (size_t)(ea - 256) * HD + l4 * 8;
            }
            f32x4 acc[4][4] = {};
            #pragma unroll
            for (int kk = 0; kk < 16; ++kk) {             // x part
                bf16x8 a[4], b[4];
                #pragma unroll
                for (int fr = 0; fr < 4; ++fr)
                    a[fr] = *reinterpret_cast<const bf16x8*>(xa[fr] + kk * 32);
                #pragma unroll
                for (int g = 0; g < 4; ++g)
                    b[g] = *reinterpret_cast<const bf16x8*>(&Wl[((g * 32 + kk) * 64 + lane) * 8]);
                #pragma unroll
                for (int fr = 0; fr < 4; ++fr)
                    #pragma unroll
                    for (int g = 0; g < 4; ++g)
                        acc[fr][g] = __builtin_amdgcn_mfma_f32_16x16x32_bf16(a[fr], b[g], acc[fr][g], 0, 0, 0);
            }
            #pragma unroll
            for (int kk = 0; kk < 16; ++kk) {             // h part (s >= SPLIT > 0)
                bf16x8 a[4], b[4];
                #pragma unroll
                for (int fr = 0; fr < 4; ++fr)
                    a[fr] = *reinterpret_cast<const bf16x8*>(ha[fr] + kk * 32);
                #pragma unroll
                for (int g = 0; g < 4; ++g)
                    b[g] = *reinterpret_cast<const bf16x8*>(&Wl[((g * 32 + 16 + kk) * 64 + lane) * 8]);
                #pragma unroll
                for (int fr = 0; fr < 4; ++fr)
                    #pragma unroll
                    for (int g = 0; g < 4; ++g)
                        acc[fr][g] = __builtin_amdgcn_mfma_f32_16x16x32_bf16(a[fr], b[g], acc[fr][g], 0, 0, 0);
            }

            #pragma unroll
            for (int fr = 0; fr < 4; ++fr) {
                #pragma unroll
                for (int r = 0; r < 4; ++r) {
                    int ie = grp * 64 + fr * 16 + l4 * 4 + r;
                    if (ie < gcnt) {
                        u32 ee = entries[goff + ie];
                        float cprev = cxs[(size_t)(ee - 256) * HD + hcol];
                        float ig = sigm(acc[fr][0][r] + bI);
                        float fg = sigm(acc[fr][1][r] + bF);
                        float gc = tanh_f(acc[fr][2][r] + bG);
                        float og = sigm(acc[fr][3][r] + bO);
                        float c = fg * cprev + ig * gc;
                        float h = og * tanh_f(c);
                        size_t o = (size_t)ee * HD + hcol;
                        __builtin_nontemporal_store(h, hxs0 + o);
                        __builtin_nontemporal_store(h, hxs1 + o);
                        cxs[o] = c;
                        unsigned mine = (unsigned)f2b(h);
                        unsigned oth  = (unsigned)__shfl_xor((int)mine, 1, 64);
                        if (!(lane & 1))
                            *reinterpret_cast<unsigned*>(hb16 + o) =
                                (mine & 0xffffu) | (oth << 16);
                    }
                }
            }
        }

        if (s == maxd) break;
        // ---- inter-depth barrier (R4 protocol); weights stay in LDS ----
        asm volatile("s_waitcnt vmcnt(0)" ::: "memory");
        __syncthreads();
        ++iter;
        if (tid == 0) {
            __hip_atomic_fetch_add(bar, 1u, __ATOMIC_RELEASE, __HIP_MEMORY_SCOPE_AGENT);
            while (__hip_atomic_load(bar, __ATOMIC_RELAXED, __HIP_MEMORY_SCOPE_AGENT) < iter * (unsigned)NDEEP)
                __builtin_amdgcn_s_sleep(1);
            (void)__hip_atomic_load(bar, __ATOMIC_ACQUIRE, __HIP_MEMORY_SCOPE_AGENT);
        }
        __syncthreads();
    }
}

// ===========================================================================
// FALLBACK PATH (round-1, validated): per-step launches, fp32 VALU
// ===========================================================================
__global__ void prep_r1(const float* __restrict__ W_ih, const float* __restrict__ W_hh,
                        const float* __restrict__ b_ih, const float* __restrict__ b_hh,
                        float* __restrict__ WcT, float* __restrict__ bc) {
    int idx = blockIdx.x * 256 + threadIdx.x;
    int k = idx >> 11;
    int j = idx & (G4 - 1);
    float v = (k < ID) ? W_ih[(size_t)j * ID + k] : W_hh[(size_t)j * HD + (k - ID)];
    WcT[idx] = v;
    if (idx < G4) bc[idx] = b_ih[idx] + b_hh[idx];
}

__launch_bounds__(512, 2)
__global__ void lstm_step_r1(int t, int use_ws,
                             const float* __restrict__ feat, const int* __restrict__ mask,
                             const float* __restrict__ W_ih, const float* __restrict__ W_hh,
                             const float* __restrict__ b_ih, const float* __restrict__ b_hh,
                             const float* __restrict__ WcT, const float* __restrict__ bc,
                             float* __restrict__ out) {
    __shared__ float4 xh4[16][256];
    const int tid = threadIdx.x;
    const int c0 = blockIdx.x * 32;
    const int b0 = blockIdx.y * 16;
    float* hxs0 = out;
    float* hxs1 = out + TBH;
    float* cxs  = out + 2 * TBH;

    for (int e = tid; e < 16 * 256; e += 512) {
        int bl = e >> 8, q = e & 255, b = b0 + bl;
        float4 v;
        if (q < 128) {
            v = reinterpret_cast<const float4*>(feat + ((size_t)t * BB + b) * ID)[q];
        } else if (t == 0) {
            v = make_float4(0.f, 0.f, 0.f, 0.f);
        } else {
            float keep = 1.0f - (float)mask[t * BB + b];
            v = reinterpret_cast<const float4*>(hxs0 + ((size_t)(t - 1) * BB + b) * HD)[q - 128];
            v.x *= keep; v.y *= keep; v.z *= keep; v.w *= keep;
        }
        xh4[bl][q] = v;
    }
    __syncthreads();

    const int lc = tid & 127, bh = tid >> 7;
    const int j = (lc >> 5) * HD + c0 + (lc & 31);
    float acc[4] = {0.f, 0.f, 0.f, 0.f};
    if (use_ws) {
        for (int k = 0; k < KT; k += 4) {
            float w0 = WcT[(size_t)(k + 0) * G4 + j];
            float w1 = WcT[(size_t)(k + 1) * G4 + j];
            float w2 = WcT[(size_t)(k + 2) * G4 + j];
            float w3 = WcT[(size_t)(k + 3) * G4 + j];
            #pragma unroll
            for (int i = 0; i < 4; ++i) {
                float4 x = xh4[bh * 4 + i][k >> 2];
                acc[i] = fmaf(x.x, w0, acc[i]); acc[i] = fmaf(x.y, w1, acc[i]);
                acc[i] = fmaf(x.z, w2, acc[i]); acc[i] = fmaf(x.w, w3, acc[i]);
            }
        }
    } else {
        const float4* wi = reinterpret_cast<const float4*>(W_ih + (size_t)j * ID);
        const float4* wh = reinterpret_cast<const float4*>(W_hh + (size_t)j * HD);
        for (int k = 0; k < KT; k += 4) {
            float4 wv = (k < ID) ? wi[k >> 2] : wh[(k - ID) >> 2];
            #pragma unroll
            for (int i = 0; i < 4; ++i) {
                float4 x = xh4[bh * 4 + i][k >> 2];
                acc[i] = fmaf(x.x, wv.x, acc[i]); acc[i] = fmaf(x.y, wv.y, acc[i]);
                acc[i] = fmaf(x.z, wv.z, acc[i]); acc[i] = fmaf(x.w, wv.w, acc[i]);
            }
        }
    }
    float gbias = use_ws ? bc[j] : (b_ih[j] + b_hh[j]);
    __syncthreads();
    float* gbuf = reinterpret_cast<float*>(xh4);
    #pragma unroll
    for (int i = 0; i < 4; ++i) gbuf[lc * 16 + bh * 4 + i] = acc[i] + gbias;
    __syncthreads();
    {
        int hc = tid & 31, bl = tid >> 5, b = b0 + bl;
        float keep = 1.0f - (float)mask[t * BB + b];
        float cp = 0.f;
        if (t > 0) cp = cxs[((size_t)(t - 1) * BB + b) * HD + c0 + hc];
        cp *= keep;
        float ig = gbuf[(0 * 32 + hc) * 16 + bl];
        float fg = gbuf[(1 * 32 + hc) * 16 + bl];
        float gg = gbuf[(2 * 32 + hc) * 16 + bl];
        float og = gbuf[(3 * 32 + hc) * 16 + bl];
        ig = 1.0f / (1.0f + __expf(-ig));
        fg = 1.0f / (1.0f + __expf(-fg));
        gg = tanhf(gg);
        og = 1.0f / (1.0f + __expf(-og));
        float cn = fg * cp + ig * gg;
        float hn = og * tanhf(cn);
        size_t o = ((size_t)t * BB + b) * HD + c0 + hc;
        hxs0[o] = hn; hxs1[o] = hn; cxs[o] = cn;
    }
}

// ===========================================================================
extern "C" void kernel_launch(void* const* d_in, const int* in_sizes, int n_in,
                              void* d_out, int out_size, void* d_ws, size_t ws_size,
                              hipStream_t stream) {
    const float* feat = (const float*)d_in[0];
    const int*   mask = (const int*)d_in[1];
    const float* W_ih = (const float*)d_in[2];
    const float* W_hh = (const float*)d_in[3];
    const float* b_ih = (const float*)d_in[4];
    const float* b_hh = (const float*)d_in[5];
    float* out = (float*)d_out;

    size_t offWf  = 0;                                               // 4 MB
    size_t offBc  = offWf  + (size_t)G4 * KT * sizeof(u16);
    size_t offXb  = offBc  + (size_t)G4 * sizeof(float);             // +8 KB
    size_t offHb  = offXb  + (size_t)TT * BB * ID * sizeof(u16);     // +64 MB
    size_t offDm  = offHb  + (size_t)TT * BB * HD * sizeof(u16);     // +64 MB
    size_t offCnt = offDm  + (size_t)TT * BB;                        // +64 KB
    size_t offOff = offCnt + 2048;                                   // counts[257]
    size_t offBar = offOff + 2048;
    size_t offEnt = offBar + 1024;
    size_t need   = offEnt + ((size_t)TT * BB + 256) * sizeof(u32);

    if (d_ws != nullptr && ws_size >= need) {
        char* ws = (char*)d_ws;
        u16*   Wfrag = (u16*)(ws + offWf);
        float* bc    = (float*)(ws + offBc);
        u16*   xb    = (u16*)(ws + offXb);
        u16*   hb16  = (u16*)(ws + offHb);
        u8*    dmap  = (u8*)(ws + offDm);
        u32*   counts  = (u32*)(ws + offCnt);
        u32*   offsets = (u32*)(ws + offOff);
        unsigned* bar  = (unsigned*)(ws + offBar);
        u32*   entries = (u32*)(ws + offEnt);

        prep_w<<<1024, 256, 0, stream>>>(W_ih, W_hh, b_ih, b_hh, Wfrag, bc, bar);
        prep_x<<<16384, 256, 0, stream>>>(feat, xb);
        seg_all<<<1, 256, 0, stream>>>(mask, dmap, counts, offsets, entries);
        for (int s = 0; s < SPLIT; ++s)
            lstm_depth<<<DGRID, 512, 0, stream>>>(s, counts, offsets, entries,
                                                  Wfrag, xb, hb16, bc, out);
        lstm_deep<<<NDEEP, 512, 0, stream>>>(counts, offsets, entries,
                                             Wfrag, xb, hb16, bc, out, bar);
    } else {
        float* WcT = (float*)d_ws;
        float* bcf = WcT + (size_t)KT * G4;
        const size_t ws_needed = ((size_t)KT * G4 + G4) * sizeof(float);
        int use_ws = (d_ws != nullptr && ws_size >= ws_needed) ? 1 : 0;
        if (use_ws)
            prep_r1<<<(KT * G4) / 256, 256, 0, stream>>>(W_ih, W_hh, b_ih, b_hh, WcT, bcf);
        dim3 grid(16, 16);
        for (int t = 0; t < TT; ++t)
            lstm_step_r1<<<grid, 512, 0, stream>>>(t, use_ws, feat, mask,
                                                   W_ih, W_hh, b_ih, b_hh, WcT, bcf, out);
    }
}

// Round 20
// 1596.061 us; speedup vs baseline: 1.1314x; 1.0790x over previous
//
#include <hip/hip_runtime.h>
#include <math.h>

#define TT 256
#define BB 256
#define ID 512
#define HD 512
#define G4 2048            // 4*H
#define KT 1024            // IN + H
#define TBH ((size_t)TT * BB * HD)
#define SPLIT 4            // depths [0,SPLIT) get dedicated launches
#define DGRID 512          // lstm_depth grid (multiple of 4)
#define NDEEP 128          // lstm_deep blocks (1/CU; 4 row-split per hcol set)

typedef short bf16x8 __attribute__((ext_vector_type(8)));
typedef float f32x4  __attribute__((ext_vector_type(4)));
typedef unsigned short u16;
typedef unsigned char  u8;
typedef unsigned int   u32;
typedef u16  u16x8 __attribute__((ext_vector_type(8)));

__device__ __forceinline__ u16 f2b(float f) {
    unsigned u = __builtin_bit_cast(unsigned, f);
    return (u16)((u + 0x7fffu + ((u >> 16) & 1u)) >> 16);   // RNE
}
__device__ __forceinline__ float sigm(float x) { return 1.f / (1.f + __expf(-x)); }
__device__ __forceinline__ float tanh_f(float x) { return 1.f - 2.f / (1.f + __expf(2.f * x)); }

// ===========================================================================
// FAST PATH (needs ~133 MB ws)
// ===========================================================================

// Wfrag: fused-K weights, fragment-sequential per (nb, gate, hc) slice
// (validated R11-R19). Also zeroes the deep-kernel barrier.
__global__ void prep_w(const float* __restrict__ W_ih,
                       const float* __restrict__ W_hh,
                       const float* __restrict__ b_ih,
                       const float* __restrict__ b_hh,
                       u16* __restrict__ Wfrag, float* __restrict__ bc,
                       unsigned* __restrict__ bar) {
    int idx = blockIdx.x * 256 + threadIdx.x;   // 0 .. 262143 (16B chunks)
    int s  = idx >> 11;
    int kk = (idx >> 6) & 31;
    int l  = idx & 63;
    int nb = s >> 3, G = (s >> 1) & 3, hc = s & 1;
    int col = G * 512 + nb * 32 + hc * 16 + (l & 15);
    int k0  = kk * 32 + (l >> 4) * 8;
    const float* src = (k0 < ID) ? (W_ih + (size_t)col * ID + k0)
                                 : (W_hh + (size_t)col * HD + (k0 - ID));
    u16x8 pk;
    #pragma unroll
    for (int e = 0; e < 8; ++e) pk[e] = f2b(src[e]);
    *reinterpret_cast<u16x8*>(Wfrag + (size_t)idx * 8) = pk;
    if (idx < G4) bc[idx] = b_ih[idx] + b_hh[idx];
    if (idx < 256) bar[idx] = 0u;
}

// feat (f32) -> xb (bf16, row-major) once.
__global__ void prep_x(const float* __restrict__ feat, u16* __restrict__ xb) {
    size_t base = ((size_t)blockIdx.x * 256 + threadIdx.x) * 8;
    const float4* src = reinterpret_cast<const float4*>(feat + base);
    float4 v0 = src[0], v1 = src[1];
    u16x8 pk;
    pk[0]=f2b(v0.x); pk[1]=f2b(v0.y); pk[2]=f2b(v0.z); pk[3]=f2b(v0.w);
    pk[4]=f2b(v1.x); pk[5]=f2b(v1.y); pk[6]=f2b(v1.z); pk[7]=f2b(v1.w);
    *reinterpret_cast<u16x8*>(xb + base) = pk;
}

// Segment bucketing (deterministic, no atomics; validated R14-R19).
// entries sorted by (d, t, b): entries[slot] = (t<<8)|b. counts[256] = maxd.
__launch_bounds__(256, 1)
__global__ void seg_all(const int* __restrict__ mask,
                        u8*  __restrict__ dmap,
                        u32* __restrict__ counts,
                        u32* __restrict__ offsets,
                        u32* __restrict__ entries) {
    __shared__ u16 c2[256 * 256];   // [d][t] counters -> cursors
    __shared__ u32 aux[256];
    const int tid = threadIdx.x;

    for (int d = 0; d < 256; ++d) c2[d * 256 + tid] = 0;
    __syncthreads();

    {   // phase 1 (tid = b): depths -> dmap
        int d = 0;
        for (int t = 0; t < 256; ++t) {
            int m = mask[t * 256 + tid];
            d = (t == 0) ? 0 : (m ? 0 : d + 1);
            dmap[t * 256 + tid] = (u8)d;
        }
    }
    __syncthreads();

    // phase 2 (tid = t): per-(d,t) counts
    for (int b = 0; b < 256; ++b)
        c2[(int)dmap[tid * 256 + b] * 256 + tid]++;
    __syncthreads();

    {   // phase 3 (tid = d): exclusive prefix over t; total -> aux
        u32 run = 0;
        for (int t = 0; t < 256; ++t) {
            u32 v = c2[tid * 256 + t];
            c2[tid * 256 + t] = (u16)run;
            run += v;
        }
        aux[tid] = run;
    }
    __syncthreads();

    // phase 4: serial prefix over depths + max depth
    if (tid == 0) {
        u32 run = 0; int maxd = 0;
        for (int d = 0; d < 256; ++d) {
            u32 v = aux[d];
            counts[d]  = v;
            offsets[d] = run;
            aux[d] = run;
            run += v;
            if (v) maxd = d;
        }
        counts[256] = (u32)maxd;
    }
    __syncthreads();

    {   // phase 5 (tid = d): add depth offset -> cursors
        u32 o = aux[tid];
        for (int t = 0; t < 256; ++t)
            c2[tid * 256 + t] = (u16)(c2[tid * 256 + t] + o);
    }
    __syncthreads();

    // phase 6 (tid = t): scatter; cursor column owned per-t thread
    for (int b = 0; b < 256; ++b) {
        int d = dmap[tid * 256 + b];
        u32 slot = c2[d * 256 + tid]++;
        entries[slot] = (u32)((tid << 8) | b);
    }
}

// One job = 64 gathered rows x 128 hcols (cg) x 4 gates, K fused.
// Wave hq in [0,8): acc[fr][g]; A reused 4x, B reused 4x. No LDS/barriers.
// Store policy = R14/R17: NT for hxs0/hxs1, cached for cxs/hb16.
__device__ __forceinline__ void depth_job(
    int s, int j, int gcnt, int goff,
    const u32* __restrict__ entries,
    const u16* __restrict__ Wfrag,
    const u16* __restrict__ xb,
    u16* __restrict__ hb16,
    const float* __restrict__ bc,
    float* __restrict__ out, int tid)
{
    const int w = tid >> 6, lane = tid & 63;
    const int l15 = lane & 15, l4 = lane >> 4;
    const int cg = j & 3, jt = j >> 2;
    const int hq = w;

    float* hxs0 = out;
    float* hxs1 = out + TBH;
    float* cxs  = out + 2 * TBH;

    const u16* xa[4];
    const u16* ha[4];
    #pragma unroll
    for (int fr = 0; fr < 4; ++fr) {
        int ia = jt * 64 + fr * 16 + l15;
        if (ia >= gcnt) ia = gcnt - 1;
        u32 ea = entries[goff + ia];              // ea == t*256 + b
        xa[fr] = xb   + (size_t)ea * ID + l4 * 8;
        ha[fr] = hb16 + (size_t)(ea - 256) * HD + l4 * 8;  // valid when s>0
    }

    const size_t SL = (size_t)32 * 64 * 8;
    const int hb = cg * 8 + hq;
    const int nb = hb >> 1, hc = hb & 1;
    const u16* wb[4];
    #pragma unroll
    for (int g = 0; g < 4; ++g)
        wb[g] = Wfrag + (size_t)((nb * 4 + g) * 2 + hc) * SL;

    f32x4 acc[4][4] = {};                         // [fr][g]
    #pragma unroll
    for (int kk = 0; kk < 16; ++kk) {             // x part (k 0..511)
        bf16x8 a[4], b[4];
        #pragma unroll
        for (int fr = 0; fr < 4; ++fr)
            a[fr] = *reinterpret_cast<const bf16x8*>(xa[fr] + kk * 32);
        #pragma unroll
        for (int g = 0; g < 4; ++g)
            b[g] = *reinterpret_cast<const bf16x8*>(wb[g] + (size_t)(kk * 64 + lane) * 8);
        #pragma unroll
        for (int fr = 0; fr < 4; ++fr)
            #pragma unroll
            for (int g = 0; g < 4; ++g)
                acc[fr][g] = __builtin_amdgcn_mfma_f32_16x16x32_bf16(a[fr], b[g], acc[fr][g], 0, 0, 0);
    }
    if (s > 0) {                                  // h part (k 512..1023)
        #pragma unroll
        for (int kk = 0; kk < 16; ++kk) {
            bf16x8 a[4], b[4];
            #pragma unroll
            for (int fr = 0; fr < 4; ++fr)
                a[fr] = *reinterpret_cast<const bf16x8*>(ha[fr] + kk * 32);
            #pragma unroll
            for (int g = 0; g < 4; ++g)
                b[g] = *reinterpret_cast<const bf16x8*>(wb[g] + (size_t)((16 + kk) * 64 + lane) * 8);
            #pragma unroll
            for (int fr = 0; fr < 4; ++fr)
                #pragma unroll
                for (int g = 0; g < 4; ++g)
                    acc[fr][g] = __builtin_amdgcn_mfma_f32_16x16x32_bf16(a[fr], b[g], acc[fr][g], 0, 0, 0);
        }
    }

    const int hcol = cg * 128 + hq * 16 + l15;
    const float bI = bc[hcol],        bF = bc[512 + hcol];
    const float bG = bc[1024 + hcol], bO = bc[1536 + hcol];
    #pragma unroll
    for (int fr = 0; fr < 4; ++fr) {
        #pragma unroll
        for (int r = 0; r < 4; ++r) {
            int ie = jt * 64 + fr * 16 + l4 * 4 + r;   // uniform across l15
            if (ie < gcnt) {
                u32 ee = entries[goff + ie];
                float cprev = (s > 0) ? cxs[(size_t)(ee - 256) * HD + hcol] : 0.f;
                float ig = sigm(acc[fr][0][r] + bI);
                float fg = sigm(acc[fr][1][r] + bF);
                float gc = tanh_f(acc[fr][2][r] + bG);
                float og = sigm(acc[fr][3][r] + bO);
                float c = fg * cprev + ig * gc;
                float h = og * tanh_f(c);
                size_t o = (size_t)ee * HD + hcol;
                __builtin_nontemporal_store(h, hxs0 + o);
                __builtin_nontemporal_store(h, hxs1 + o);
                cxs[o] = c;                       // cached: read by next depth
                unsigned mine = (unsigned)f2b(h);
                unsigned oth  = (unsigned)__shfl_xor((int)mine, 1, 64);
                if (!(lane & 1))
                    *reinterpret_cast<unsigned*>(hb16 + o) =
                        (mine & 0xffffu) | (oth << 16);
            }
        }
    }
}

// Dedicated launches for the big depths [0, SPLIT).
__launch_bounds__(512, 2)
__global__ void lstm_depth(int s,
                           const u32* __restrict__ counts,
                           const u32* __restrict__ offsets,
                           const u32* __restrict__ entries,
                           const u16* __restrict__ Wfrag,
                           const u16* __restrict__ xb,
                           u16* __restrict__ hb16,
                           const float* __restrict__ bc,
                           float* __restrict__ out) {
    int gcnt = counts[s];
    if (gcnt == 0) return;
    int goff = offsets[s];
    int njobs = ((gcnt + 63) >> 6) << 2;
    for (int j = blockIdx.x; j < njobs; j += DGRID)   // cg = j&3 const per block
        depth_job(s, j, gcnt, goff, entries, Wfrag, xb, hb16, bc, out, threadIdx.x);
}

// Persistent deep kernel: all depths s in [SPLIT, maxd] in ONE launch.
// 128 blocks: bid -> (hb = bid>>2 hcol-16 set, rs = bid&3 row-split).
// The 4 blocks sharing hb stage identical 128 KB LDS weight slices and
// partition row-groups (grp = rs*8 + w, stride 32). Weights survive the
// barrier's acquire-inv in LDS. R4-proven barrier between depths.
__launch_bounds__(512, 1)
__global__ void lstm_deep(const u32* __restrict__ counts,
                          const u32* __restrict__ offsets,
                          const u32* __restrict__ entries,
                          const u16* __restrict__ Wfrag,
                          const u16* __restrict__ xb,
                          u16* __restrict__ hb16,
                          const float* __restrict__ bc,
                          float* __restrict__ out,
                          unsigned* bar) {
    __shared__ u16 Wl[4 * 32 * 64 * 8];   // 128 KB: [g][kk][lane][8]
    const int tid = threadIdx.x;
    const int hb = blockIdx.x >> 2;       // hcol-16 block
    const int rs = blockIdx.x & 3;        // row-split
    const int w = tid >> 6, lane = tid & 63;
    const int l15 = lane & 15, l4 = lane >> 4;

    const int maxd = (int)counts[256];
    if (maxd < SPLIT) return;

    {   // stage this block's weight slices (4 gates x 32 kk x 64 lanes x 16B)
        const int nb = hb >> 1, hc = hb & 1;
        for (int c = tid; c < 4 * 32 * 64; c += 512) {
            int g = c >> 11;
            int rem = c & 2047;
            u16x8 v = *reinterpret_cast<const u16x8*>(
                Wfrag + ((size_t)((nb * 4 + g) * 2 + hc) * 2048 + rem) * 8);
            *reinterpret_cast<u16x8*>(&Wl[(size_t)c * 8]) = v;
        }
    }
    __syncthreads();

    float* hxs0 = out;
    float* hxs1 = out + TBH;
    float* cxs  = out + 2 * TBH;
    const int hcol = hb * 16 + l15;
    const float bI = bc[hcol],        bF = bc[512 + hcol];
    const float bG = bc[1024 + hcol], bO = bc[1536 + hcol];

    unsigned iter = 0;
    for (int s = SPLIT; s <= maxd; ++s) {
        const int gcnt = counts[s];
        const int goff = offsets[s];
        const int ngrp = (gcnt + 63) >> 6;

        for (int grp = rs * 8 + w; grp < ngrp; grp += 32) {
            const u16* xa[4];
            const u16* ha[4];
            #pragma unroll
            for (int fr = 0; fr < 4; ++fr) {
                int ia = grp * 64 + fr * 16 + l15;
                if (ia >= gcnt) ia = gcnt - 1;
                u32 ea = entries[goff + ia];
                xa[fr] = xb   + (size_t)ea * ID + l4 * 8;
                ha[fr] = hb16 + (size_t)(ea - 256) * HD + l4 * 8;
            }
            f32x4 acc[4][4] = {};
            #pragma unroll
            for (int kk = 0; kk < 16; ++kk) {             // x part
                bf16x8 a[4], b[4];
                #pragma unroll
                for (int fr = 0; fr < 4; ++fr)
                    a[fr] = *reinterpret_cast<const bf16x8*>(xa[fr] + kk * 32);
                #pragma unroll
                for (int g = 0; g < 4; ++g)
                    b[g] = *reinterpret_cast<const bf16x8*>(&Wl[((g * 32 + kk) * 64 + lane) * 8]);
                #pragma unroll
                for (int fr = 0; fr < 4; ++fr)
                    #pragma unroll
                    for (int g = 0; g < 4; ++g)
                        acc[fr][g] = __builtin_amdgcn_mfma_f32_16x16x32_bf16(a[fr], b[g], acc[fr][g], 0, 0, 0);
            }
            #pragma unroll
            for (int kk = 0; kk < 16; ++kk) {             // h part (s >= SPLIT > 0)
                bf16x8 a[4], b[4];
                #pragma unroll
                for (int fr = 0; fr < 4; ++fr)
                    a[fr] = *reinterpret_cast<const bf16x8*>(ha[fr] + kk * 32);
                #pragma unroll
                for (int g = 0; g < 4; ++g)
                    b[g] = *reinterpret_cast<const bf16x8*>(&Wl[((g * 32 + 16 + kk) * 64 + lane) * 8]);
                #pragma unroll
                for (int fr = 0; fr < 4; ++fr)
                    #pragma unroll
                    for (int g = 0; g < 4; ++g)
                        acc[fr][g] = __builtin_amdgcn_mfma_f32_16x16x32_bf16(a[fr], b[g], acc[fr][g], 0, 0, 0);
            }

            #pragma unroll
            for (int fr = 0; fr < 4; ++fr) {
                #pragma unroll
                for (int r = 0; r < 4; ++r) {
                    int ie = grp * 64 + fr * 16 + l4 * 4 + r;
                    if (ie < gcnt) {
                        u32 ee = entries[goff + ie];
                        float cprev = cxs[(size_t)(ee - 256) * HD + hcol];
                        float ig = sigm(acc[fr][0][r] + bI);
                        float fg = sigm(acc[fr][1][r] + bF);
                        float gc = tanh_f(acc[fr][2][r] + bG);
                        float og = sigm(acc[fr][3][r] + bO);
                        float c = fg * cprev + ig * gc;
                        float h = og * tanh_f(c);
                        size_t o = (size_t)ee * HD + hcol;
                        __builtin_nontemporal_store(h, hxs0 + o);
                        __builtin_nontemporal_store(h, hxs1 + o);
                        cxs[o] = c;
                        unsigned mine = (unsigned)f2b(h);
                        unsigned oth  = (unsigned)__shfl_xor((int)mine, 1, 64);
                        if (!(lane & 1))
                            *reinterpret_cast<unsigned*>(hb16 + o) =
                                (mine & 0xffffu) | (oth << 16);
                    }
                }
            }
        }

        if (s == maxd) break;
        // ---- inter-depth barrier (R4 protocol); weights stay in LDS ----
        asm volatile("s_waitcnt vmcnt(0)" ::: "memory");
        __syncthreads();
        ++iter;
        if (tid == 0) {
            __hip_atomic_fetch_add(bar, 1u, __ATOMIC_RELEASE, __HIP_MEMORY_SCOPE_AGENT);
            while (__hip_atomic_load(bar, __ATOMIC_RELAXED, __HIP_MEMORY_SCOPE_AGENT) < iter * (unsigned)NDEEP)
                __builtin_amdgcn_s_sleep(1);
            (void)__hip_atomic_load(bar, __ATOMIC_ACQUIRE, __HIP_MEMORY_SCOPE_AGENT);
        }
        __syncthreads();
    }
}

// ===========================================================================
// FALLBACK PATH (round-1, validated): per-step launches, fp32 VALU
// ===========================================================================
__global__ void prep_r1(const float* __restrict__ W_ih, const float* __restrict__ W_hh,
                        const float* __restrict__ b_ih, const float* __restrict__ b_hh,
                        float* __restrict__ WcT, float* __restrict__ bc) {
    int idx = blockIdx.x * 256 + threadIdx.x;
    int k = idx >> 11;
    int j = idx & (G4 - 1);
    float v = (k < ID) ? W_ih[(size_t)j * ID + k] : W_hh[(size_t)j * HD + (k - ID)];
    WcT[idx] = v;
    if (idx < G4) bc[idx] = b_ih[idx] + b_hh[idx];
}

__launch_bounds__(512, 2)
__global__ void lstm_step_r1(int t, int use_ws,
                             const float* __restrict__ feat, const int* __restrict__ mask,
                             const float* __restrict__ W_ih, const float* __restrict__ W_hh,
                             const float* __restrict__ b_ih, const float* __restrict__ b_hh,
                             const float* __restrict__ WcT, const float* __restrict__ bc,
                             float* __restrict__ out) {
    __shared__ float4 xh4[16][256];
    const int tid = threadIdx.x;
    const int c0 = blockIdx.x * 32;
    const int b0 = blockIdx.y * 16;
    float* hxs0 = out;
    float* hxs1 = out + TBH;
    float* cxs  = out + 2 * TBH;

    for (int e = tid; e < 16 * 256; e += 512) {
        int bl = e >> 8, q = e & 255, b = b0 + bl;
        float4 v;
        if (q < 128) {
            v = reinterpret_cast<const float4*>(feat + ((size_t)t * BB + b) * ID)[q];
        } else if (t == 0) {
            v = make_float4(0.f, 0.f, 0.f, 0.f);
        } else {
            float keep = 1.0f - (float)mask[t * BB + b];
            v = reinterpret_cast<const float4*>(hxs0 + ((size_t)(t - 1) * BB + b) * HD)[q - 128];
            v.x *= keep; v.y *= keep; v.z *= keep; v.w *= keep;
        }
        xh4[bl][q] = v;
    }
    __syncthreads();

    const int lc = tid & 127, bh = tid >> 7;
    const int j = (lc >> 5) * HD + c0 + (lc & 31);
    float acc[4] = {0.f, 0.f, 0.f, 0.f};
    if (use_ws) {
        for (int k = 0; k < KT; k += 4) {
            float w0 = WcT[(size_t)(k + 0) * G4 + j];
            float w1 = WcT[(size_t)(k + 1) * G4 + j];
            float w2 = WcT[(size_t)(k + 2) * G4 + j];
            float w3 = WcT[(size_t)(k + 3) * G4 + j];
            #pragma unroll
            for (int i = 0; i < 4; ++i) {
                float4 x = xh4[bh * 4 + i][k >> 2];
                acc[i] = fmaf(x.x, w0, acc[i]); acc[i] = fmaf(x.y, w1, acc[i]);
                acc[i] = fmaf(x.z, w2, acc[i]); acc[i] = fmaf(x.w, w3, acc[i]);
            }
        }
    } else {
        const float4* wi = reinterpret_cast<const float4*>(W_ih + (size_t)j * ID);
        const float4* wh = reinterpret_cast<const float4*>(W_hh + (size_t)j * HD);
        for (int k = 0; k < KT; k += 4) {
            float4 wv = (k < ID) ? wi[k >> 2] : wh[(k - ID) >> 2];
            #pragma unroll
            for (int i = 0; i < 4; ++i) {
                float4 x = xh4[bh * 4 + i][k >> 2];
                acc[i] = fmaf(x.x, wv.x, acc[i]); acc[i] = fmaf(x.y, wv.y, acc[i]);
                acc[i] = fmaf(x.z, wv.z, acc[i]); acc[i] = fmaf(x.w, wv.w, acc[i]);
            }
        }
    }
    float gbias = use_ws ? bc[j] : (b_ih[j] + b_hh[j]);
    __syncthreads();
    float* gbuf = reinterpret_cast<float*>(xh4);
    #pragma unroll
    for (int i = 0; i < 4; ++i) gbuf[lc * 16 + bh * 4 + i] = acc[i] + gbias;
    __syncthreads();
    {
        int hc = tid & 31, bl = tid >> 5, b = b0 + bl;
        float keep = 1.0f - (float)mask[t * BB + b];
        float cp = 0.f;
        if (t > 0) cp = cxs[((size_t)(t - 1) * BB + b) * HD + c0 + hc];
        cp *= keep;
        float ig = gbuf[(0 * 32 + hc) * 16 + bl];
        float fg = gbuf[(1 * 32 + hc) * 16 + bl];
        float gg = gbuf[(2 * 32 + hc) * 16 + bl];
        float og = gbuf[(3 * 32 + hc) * 16 + bl];
        ig = 1.0f / (1.0f + __expf(-ig));
        fg = 1.0f / (1.0f + __expf(-fg));
        gg = tanhf(gg);
        og = 1.0f / (1.0f + __expf(-og));
        float cn = fg * cp + ig * gg;
        float hn = og * tanhf(cn);
        size_t o = ((size_t)t * BB + b) * HD + c0 + hc;
        hxs0[o] = hn; hxs1[o] = hn; cxs[o] = cn;
    }
}

// ===========================================================================
extern "C" void kernel_launch(void* const* d_in, const int* in_sizes, int n_in,
                              void* d_out, int out_size, void* d_ws, size_t ws_size,
                              hipStream_t stream) {
    const float* feat = (const float*)d_in[0];
    const int*   mask = (const int*)d_in[1];
    const float* W_ih = (const float*)d_in[2];
    const float* W_hh = (const float*)d_in[3];
    const float* b_ih = (const float*)d_in[4];
    const float* b_hh = (const float*)d_in[5];
    float* out = (float*)d_out;

    size_t offWf  = 0;                                               // 4 MB
    size_t offBc  = offWf  + (size_t)G4 * KT * sizeof(u16);
    size_t offXb  = offBc  + (size_t)G4 * sizeof(float);             // +8 KB
    size_t offHb  = offXb  + (size_t)TT * BB * ID * sizeof(u16);     // +64 MB
    size_t offDm  = offHb  + (size_t)TT * BB * HD * sizeof(u16);     // +64 MB
    size_t offCnt = offDm  + (size_t)TT * BB;                        // +64 KB
    size_t offOff = offCnt + 2048;                                   // counts[257]
    size_t offBar = offOff + 2048;
    size_t offEnt = offBar + 1024;
    size_t need   = offEnt + ((size_t)TT * BB + 256) * sizeof(u32);

    if (d_ws != nullptr && ws_size >= need) {
        char* ws = (char*)d_ws;
        u16*   Wfrag = (u16*)(ws + offWf);
        float* bc    = (float*)(ws + offBc);
        u16*   xb    = (u16*)(ws + offXb);
        u16*   hb16  = (u16*)(ws + offHb);
        u8*    dmap  = (u8*)(ws + offDm);
        u32*   counts  = (u32*)(ws + offCnt);
        u32*   offsets = (u32*)(ws + offOff);
        unsigned* bar  = (unsigned*)(ws + offBar);
        u32*   entries = (u32*)(ws + offEnt);

        prep_w<<<1024, 256, 0, stream>>>(W_ih, W_hh, b_ih, b_hh, Wfrag, bc, bar);
        prep_x<<<16384, 256, 0, stream>>>(feat, xb);
        seg_all<<<1, 256, 0, stream>>>(mask, dmap, counts, offsets, entries);
        for (int s = 0; s < SPLIT; ++s)
            lstm_depth<<<DGRID, 512, 0, stream>>>(s, counts, offsets, entries,
                                                  Wfrag, xb, hb16, bc, out);
        lstm_deep<<<NDEEP, 512, 0, stream>>>(counts, offsets, entries,
                                             Wfrag, xb, hb16, bc, out, bar);
    } else {
        float* WcT = (float*)d_ws;
        float* bcf = WcT + (size_t)KT * G4;
        const size_t ws_needed = ((size_t)KT * G4 + G4) * sizeof(float);
        int use_ws = (d_ws != nullptr && ws_size >= ws_needed) ? 1 : 0;
        if (use_ws)
            prep_r1<<<(KT * G4) / 256, 256, 0, stream>>>(W_ih, W_hh, b_ih, b_hh, WcT, bcf);
        dim3 grid(16, 16);
        for (int t = 0; t < TT; ++t)
            lstm_step_r1<<<grid, 512, 0, stream>>>(t, use_ws, feat, mask,
                                                   W_ih, W_hh, b_ih, b_hh, WcT, bcf, out);
    }
}